// Round 1
// baseline (1176.920 us; speedup 1.0000x reference)
//
#include <hip/hip_runtime.h>

#define H  1024
#define V  512
#define WV 300
#define S  64
#define N  512

// ---- workspace float offsets ----
#define WS_HALL   0
#define WS_HAT    (S*H)            // 65536
#define WS_W2V    (2*S*H)          // 131072
#define WS_CHOICE (3*S*H)          // 196608  (S*2)
#define WS_SCAL   (3*S*H + 2*S)    // 196736  (S)
#define WS_ACSUM  (3*S*H + 3*S)    // 196800  (S)
#define WS_ACCUM  (3*S*H + 4*S)    // 196864  (3*H)
#define WS_ASUM   (WS_ACCUM + 3*H) // 199936  (4)
#define WS_CTR    (WS_ASUM + 4)    // 199940  (1 uint)
#define WS_FLOATS (WS_CTR + 1)

// ---- out float offsets ----
#define OUT_EP   0                  // [S,N]
#define OUT_AC   (S*N)              // [S,V]
#define OUT_SE   (S*N + S*V)        // [S,H]
#define OUT_ALL  (OUT_SE + S*H)     // [S,N,H]
#define OUT_ACT  (OUT_ALL + (size_t)S*N*H) // [S,WV]

__device__ __forceinline__ float wave_reduce(float v) {
#pragma unroll
  for (int m = 32; m > 0; m >>= 1) v += __shfl_xor(v, m, 64);
  return v;
}
__device__ __forceinline__ float dot4(float4 a, float4 b) {
  return a.x*b.x + a.y*b.y + a.z*b.z + a.w*b.w;
}

// H_all = relu(vv@A1w^T + A1b), hat = relu(vv@W1w^T + W1b). One wave per output dot.
__global__ void k_vvmats(const float* __restrict__ vv,
                         const float* __restrict__ A1w, const float* __restrict__ A1b,
                         const float* __restrict__ W1w, const float* __restrict__ W1b,
                         float* __restrict__ ws) {
  int wid  = (blockIdx.x * blockDim.x + threadIdx.x) >> 6;
  int lane = threadIdx.x & 63;
  if (wid >= 2 * S * H) return;
  int mat = wid / (S * H);
  int rem = wid - mat * S * H;
  int t = rem >> 10, j = rem & (H - 1);
  const float* w = (mat ? W1w : A1w) + (size_t)j * H;
  const float* x = vv + (size_t)t * H;
  float sum = 0.f;
#pragma unroll
  for (int c = 0; c < 4; ++c) {
    float4 a = *(const float4*)(w + c*256 + lane*4);
    float4 b = *(const float4*)(x + c*256 + lane*4);
    sum += dot4(a, b);
  }
  sum = wave_reduce(sum);
  if (lane == 0) {
    float bias = (mat ? W1b : A1b)[j];
    ws[(mat ? WS_HAT : WS_HALL) + rem] = fmaxf(sum + bias, 0.f);
  }
}

// ac = sigmoid(H_all@A2w^T + A2b) -> out. One wave per dot.
__global__ void k_ac(const float* __restrict__ ws, const float* __restrict__ A2w,
                     const float* __restrict__ A2b, float* __restrict__ out_ac) {
  int wid  = (blockIdx.x * blockDim.x + threadIdx.x) >> 6;
  int lane = threadIdx.x & 63;
  if (wid >= S * V) return;
  int t = wid >> 9, v = wid & (V - 1);
  const float* h = ws + WS_HALL + (size_t)t * H;
  const float* w = A2w + (size_t)v * H;
  float sum = 0.f;
#pragma unroll
  for (int c = 0; c < 4; ++c) {
    float4 a = *(const float4*)(w + c*256 + lane*4);
    float4 b = *(const float4*)(h + c*256 + lane*4);
    sum += dot4(a, b);
  }
  sum = wave_reduce(sum);
  if (lane == 0) out_ac[wid] = 1.f / (1.f + __expf(-(sum + A2b[v])));
}

// choice (softmax of hat@W3w^T+W3b, keep c0,c1) and acsum = sum(ac). One block per t.
__global__ void k_choice(const float* __restrict__ ws_ro, const float* __restrict__ out_ac,
                         const float* __restrict__ W3w, const float* __restrict__ W3b,
                         float* __restrict__ ws) {
  int t = blockIdx.x, tid = threadIdx.x;
  const float* hat = ws_ro + WS_HAT + (size_t)t * H;
  float4 h4 = *(const float4*)(hat + tid * 4);
  float p[4];
#pragma unroll
  for (int r = 0; r < 3; ++r) {
    float4 w4 = *(const float4*)(W3w + (size_t)r * H + tid * 4);
    p[r] = dot4(h4, w4);
  }
  const float* ac = out_ac + (size_t)t * V;
  p[3] = ac[tid * 2] + ac[tid * 2 + 1];
  __shared__ float red[4][256];
#pragma unroll
  for (int q = 0; q < 4; ++q) red[q][tid] = p[q];
  __syncthreads();
  for (int sft = 128; sft > 0; sft >>= 1) {
    if (tid < sft) {
#pragma unroll
      for (int q = 0; q < 4; ++q) red[q][tid] += red[q][tid + sft];
    }
    __syncthreads();
  }
  if (tid == 0) {
    float l0 = red[0][0] + W3b[0], l1 = red[1][0] + W3b[1], l2 = red[2][0] + W3b[2];
    float m  = fmaxf(l0, fmaxf(l1, l2));
    float e0 = __expf(l0 - m), e1 = __expf(l1 - m), e2 = __expf(l2 - m);
    float inv = 1.f / (e0 + e1 + e2);
    ws[WS_CHOICE + t * 2]     = e0 * inv;
    ws[WS_CHOICE + t * 2 + 1] = e1 * inv;
    ws[WS_ACSUM + t]          = red[3][0];
  }
}

// w2v = concat(hat, ac)@W2w^T + W2b. One wave per dot (len 1536).
__global__ void k_w2v(const float* __restrict__ ws_ro, const float* __restrict__ out_ac,
                      const float* __restrict__ W2w, const float* __restrict__ W2b,
                      float* __restrict__ ws) {
  int wid  = (blockIdx.x * blockDim.x + threadIdx.x) >> 6;
  int lane = threadIdx.x & 63;
  if (wid >= S * H) return;
  int t = wid >> 10, j = wid & (H - 1);
  const float* w   = W2w + (size_t)j * (H + V);
  const float* hat = ws_ro + WS_HAT + (size_t)t * H;
  const float* ac  = out_ac + (size_t)t * V;
  float sum = 0.f;
#pragma unroll
  for (int c = 0; c < 4; ++c) {
    float4 a = *(const float4*)(w + c*256 + lane*4);
    float4 b = *(const float4*)(hat + c*256 + lane*4);
    sum += dot4(a, b);
  }
#pragma unroll
  for (int c = 0; c < 2; ++c) {
    float4 a = *(const float4*)(w + H + c*256 + lane*4);
    float4 b = *(const float4*)(ac + c*256 + lane*4);
    sum += dot4(a, b);
  }
  sum = wave_reduce(sum);
  if (lane == 0) ws[WS_W2V + wid] = sum + W2b[j];
}

// bar_ft = (ac/acsum)@action_emb -> out step_act. One wave per output.
__global__ void k_barft(const float* __restrict__ out_ac, const float* __restrict__ emb,
                        const float* __restrict__ ws_ro, float* __restrict__ out_act) {
  int wid  = (blockIdx.x * blockDim.x + threadIdx.x) >> 6;
  int lane = threadIdx.x & 63;
  if (wid >= S * WV) return;
  int t = wid / WV, w = wid - t * WV;
  const float* ac = out_ac + (size_t)t * V;
  float sum = 0.f;
  for (int v = lane; v < V; v += 64) sum += ac[v] * emb[(size_t)v * WV + w];
  sum = wave_reduce(sum);
  if (lane == 0) out_act[wid] = sum / ws_ro[WS_ACSUM + t];
}

// scal = bar_ft@W4w + W4b. One wave per t.
__global__ void k_scal(const float* __restrict__ out_act, const float* __restrict__ W4w,
                       const float* __restrict__ W4b, float* __restrict__ ws) {
  int wid  = (blockIdx.x * blockDim.x + threadIdx.x) >> 6;
  int lane = threadIdx.x & 63;
  if (wid >= S) return;
  const float* bf = out_act + (size_t)wid * WV;
  float sum = 0.f;
  for (int w = lane; w < WV; w += 64) sum += bf[w] * W4w[w];
  sum = wave_reduce(sum);
  if (lane == 0) ws[WS_SCAL + wid] = sum + W4b[0];
}

// Sequential 64-step scan. 64 persistent blocks x 256 threads.
// Block g owns rows g*8..g*8+7; thread owns cols 4*tid..4*tid+3 of those rows (ev in regs).
// One custom grid barrier per step; bar_et reduction via fp32 atomics into 3-rotated [H] buffer.
__global__ __launch_bounds__(256) void k_seq(
    const float* __restrict__ ev0, const float* __restrict__ ws,
    float* __restrict__ accum, float* __restrict__ asum, unsigned* __restrict__ ctr,
    float* __restrict__ out_ep, float* __restrict__ out_se, float* __restrict__ out_all) {
  const int g = blockIdx.x, tid = threadIdx.x;
  const int lane = tid & 63, wv = tid >> 6;
  const int col = tid * 4;
  __shared__ float attnS[8], prevS[8], red[8][4];
  if (tid < 8) prevS[tid] = 0.f;
  float4 ev[8];
#pragma unroll
  for (int r = 0; r < 8; ++r)
    ev[r] = *(const float4*)(ev0 + (size_t)(g * 8 + r) * H + col);
  __syncthreads();
  unsigned target = 0;
  for (int t = 0; t < S; ++t) {
    const float4 w4 = *(const float4*)(ws + WS_W2V + (size_t)t * H + col);
    float dp[8];
#pragma unroll
    for (int r = 0; r < 8; ++r) dp[r] = dot4(ev[r], w4);
#pragma unroll
    for (int r = 0; r < 8; ++r) {
#pragma unroll
      for (int m = 32; m > 0; m >>= 1) dp[r] += __shfl_xor(dp[r], m, 64);
    }
    if (lane == 0) {
#pragma unroll
      for (int r = 0; r < 8; ++r) red[r][wv] = dp[r];
    }
    __syncthreads();
    if (tid < 8) {
      float d  = red[tid][0] + red[tid][1] + red[tid][2] + red[tid][3];
      float ep = 1.f / (1.f + __expf(-d));
      out_ep[(size_t)t * N + g * 8 + tid] = ep;
      float a = ws[WS_CHOICE + 2 * t] * ep + ws[WS_CHOICE + 2 * t + 1] * prevS[tid];
      prevS[tid] = ep;
      attnS[tid] = a;
    }
    __syncthreads();
    float at[8];
#pragma unroll
    for (int r = 0; r < 8; ++r) at[r] = attnS[r];
    float4 pv = make_float4(0.f, 0.f, 0.f, 0.f);
#pragma unroll
    for (int r = 0; r < 8; ++r) {
      pv.x += at[r] * ev[r].x; pv.y += at[r] * ev[r].y;
      pv.z += at[r] * ev[r].z; pv.w += at[r] * ev[r].w;
    }
    float* acc = accum + (t % 3) * H;
    atomicAdd(acc + col + 0, pv.x);
    atomicAdd(acc + col + 1, pv.y);
    atomicAdd(acc + col + 2, pv.z);
    atomicAdd(acc + col + 3, pv.w);
    if (tid == 0) {
      float pa = 0.f;
#pragma unroll
      for (int r = 0; r < 8; ++r) pa += at[r];
      atomicAdd(asum + (t % 3), pa);
    }
    // ---- grid barrier (one per step) ----
    __threadfence();
    __syncthreads();
    target += (unsigned)gridDim.x;
    if (tid == 0) {
      __hip_atomic_fetch_add(ctr, 1u, __ATOMIC_RELEASE, __HIP_MEMORY_SCOPE_AGENT);
      while (__hip_atomic_load(ctr, __ATOMIC_ACQUIRE, __HIP_MEMORY_SCOPE_AGENT) < target)
        __builtin_amdgcn_s_sleep(2);
    }
    __syncthreads();
    // ---- phase 2: read reduced bar_et, compute kt, update ev, write out ----
    float asv = __hip_atomic_load(asum + (t % 3), __ATOMIC_RELAXED, __HIP_MEMORY_SCOPE_AGENT);
    float4 pvs;
    pvs.x = __hip_atomic_load(acc + col + 0, __ATOMIC_RELAXED, __HIP_MEMORY_SCOPE_AGENT);
    pvs.y = __hip_atomic_load(acc + col + 1, __ATOMIC_RELAXED, __HIP_MEMORY_SCOPE_AGENT);
    pvs.z = __hip_atomic_load(acc + col + 2, __ATOMIC_RELAXED, __HIP_MEMORY_SCOPE_AGENT);
    pvs.w = __hip_atomic_load(acc + col + 3, __ATOMIC_RELAXED, __HIP_MEMORY_SCOPE_AGENT);
    float inv = 1.f / asv;
    float4 bar = make_float4(pvs.x * inv, pvs.y * inv, pvs.z * inv, pvs.w * inv);
    float sc = ws[WS_SCAL + t];
    float4 kt = make_float4(fmaxf(sc * bar.x, 0.f), fmaxf(sc * bar.y, 0.f),
                            fmaxf(sc * bar.z, 0.f), fmaxf(sc * bar.w, 0.f));
    if (g == 0) *(float4*)(out_se + (size_t)t * H + col) = bar;
    // zero the rotation buffer that will be accumulated two steps from now
    if (tid < 16)
      __hip_atomic_store(accum + ((t + 2) % 3) * H + g * 16 + tid, 0.f,
                         __ATOMIC_RELAXED, __HIP_MEMORY_SCOPE_AGENT);
    if (g == 0 && tid == 16)
      __hip_atomic_store(asum + ((t + 2) % 3), 0.f, __ATOMIC_RELAXED, __HIP_MEMORY_SCOPE_AGENT);
    float* outp = out_all + (size_t)t * N * H;
#pragma unroll
    for (int r = 0; r < 8; ++r) {
      float a = at[r];
      ev[r].x = a * kt.x + (1.f - a) * ev[r].x;
      ev[r].y = a * kt.y + (1.f - a) * ev[r].y;
      ev[r].z = a * kt.z + (1.f - a) * ev[r].z;
      ev[r].w = a * kt.w + (1.f - a) * ev[r].w;
      *(float4*)(outp + (size_t)(g * 8 + r) * H + col) = ev[r];
    }
  }
}

extern "C" void kernel_launch(void* const* d_in, const int* in_sizes, int n_in,
                              void* d_out, int out_size, void* d_ws, size_t ws_size,
                              hipStream_t stream) {
  const float* vv  = (const float*)d_in[0];
  const float* ev0 = (const float*)d_in[1];
  const float* A1w = (const float*)d_in[2];
  const float* A1b = (const float*)d_in[3];
  const float* A2w = (const float*)d_in[4];
  const float* A2b = (const float*)d_in[5];
  const float* emb = (const float*)d_in[6];
  const float* W1w = (const float*)d_in[7];
  const float* W1b = (const float*)d_in[8];
  const float* W2w = (const float*)d_in[9];
  const float* W2b = (const float*)d_in[10];
  const float* W3w = (const float*)d_in[11];
  const float* W3b = (const float*)d_in[12];
  const float* W4w = (const float*)d_in[13];
  const float* W4b = (const float*)d_in[14];

  float* ws  = (float*)d_ws;
  float* out = (float*)d_out;
  float* out_ep  = out + OUT_EP;
  float* out_ac  = out + OUT_AC;
  float* out_se  = out + OUT_SE;
  float* out_all = out + OUT_ALL;
  float* out_act = out + OUT_ACT;

  // zero accum/asum/barrier-counter region (rest of ws is write-before-read)
  hipMemsetAsync(ws + WS_ACCUM, 0, (size_t)(3 * H + 4 + 1) * sizeof(float), stream);

  k_vvmats<<<(2 * S * H) / 4, 256, 0, stream>>>(vv, A1w, A1b, W1w, W1b, ws);
  k_ac    <<<(S * V) / 4,     256, 0, stream>>>(ws, A2w, A2b, out_ac);
  k_choice<<<S,               256, 0, stream>>>(ws, out_ac, W3w, W3b, ws);
  k_w2v   <<<(S * H) / 4,     256, 0, stream>>>(ws, out_ac, W2w, W2b, ws);
  k_barft <<<(S * WV + 3) / 4, 256, 0, stream>>>(out_ac, emb, ws, out_act);
  k_scal  <<<(S + 3) / 4,     256, 0, stream>>>(out_act, W4w, W4b, ws);
  k_seq   <<<64,              256, 0, stream>>>(ev0, ws,
                                                ws + WS_ACCUM, ws + WS_ASUM,
                                                (unsigned*)(ws + WS_CTR),
                                                out_ep, out_se, out_all);
}